// Round 4
// baseline (286.024 us; speedup 1.0000x reference)
//
#include <hip/hip_runtime.h>
#include <math.h>

#define INC 64
#define HID 16
#define NB 8

__device__ __forceinline__ void atomicMaxF(float* addr, float val) {
    // float-max-via-int trick: valid for mixed signs, target initialized to -inf
    if (val >= 0.0f) atomicMax((int*)addr, __float_as_int(val));
    else             atomicMin((unsigned int*)addr, __float_as_uint(val));
}

__device__ __forceinline__ void acc4(float4& sum, float4& mx, const float4 v) {
    sum.x += v.x; sum.y += v.y; sum.z += v.z; sum.w += v.w;
    mx.x = fmaxf(mx.x, v.x); mx.y = fmaxf(mx.y, v.y);
    mx.z = fmaxf(mx.z, v.z); mx.w = fmaxf(mx.w, v.w);
}

// ---------------- init workspace (ws is poisoned 0xAA before every launch) ---
__global__ void k_init(float* seg_sum, float* seg_max, int* counts, float* sm_pad) {
    int t = threadIdx.x;
    if (t < NB * INC) { seg_sum[t] = 0.0f; seg_max[t] = -INFINITY; }
    else if (t < NB * INC + NB) counts[t - NB * INC] = 0;
    else if (t < NB * INC + NB + 2) sm_pad[t - NB * INC - NB] = 0.0f; // pad row N
}

// ------------- segmented sum/max/count over sorted batch_idx -----------------
// wave = 64 lanes; lane L: sub = L>>4 (which of 4 points), ch = (L&15)*4.
// sorted batch_idx, <=7 transitions: fast path streams F with 4 explicit
// independent float4 loads in flight (separate named buffers -> compiler
// cannot collapse them into one).
__global__ void k_reduce(const float* __restrict__ F, const int* __restrict__ bidx,
                         float* __restrict__ seg_sum, float* __restrict__ seg_max,
                         int* __restrict__ counts, int N, int CHUNK) {
    int lane = threadIdx.x & 63;
    int wave = (blockIdx.x * blockDim.x + threadIdx.x) >> 6;
    int start = wave * CHUNK;
    if (start >= N) return;
    int pend = min(start + CHUNK, N);   // multiple of 4 remains (N%16==0)
    int sub = lane >> 4;
    int ch  = (lane & 15) << 2;

    int bfirst = bidx[start];
    int blast  = bidx[pend - 1];

    if (bfirst == blast) {
        float4 sum = make_float4(0.f, 0.f, 0.f, 0.f);
        float4 mx  = make_float4(-INFINITY, -INFINITY, -INFINITY, -INFINITY);
        const float* fb = F + (size_t)sub * INC + ch;
        int p = start;
        for (; p + 16 <= pend; p += 16) {
            const float* fp = fb + (size_t)p * INC;
            float4 v0 = *reinterpret_cast<const float4*>(fp);
            float4 v1 = *reinterpret_cast<const float4*>(fp + 4 * INC);
            float4 v2 = *reinterpret_cast<const float4*>(fp + 8 * INC);
            float4 v3 = *reinterpret_cast<const float4*>(fp + 12 * INC);
            acc4(sum, mx, v0); acc4(sum, mx, v1);
            acc4(sum, mx, v2); acc4(sum, mx, v3);
        }
        for (; p < pend; p += 4) {
            float4 v = *reinterpret_cast<const float4*>(fb + (size_t)p * INC);
            acc4(sum, mx, v);
        }
        // combine the 4 sub-copies (lanes differing in bits 4,5) before atomics
        #pragma unroll
        for (int msk = 16; msk < 64; msk <<= 1) {
            sum.x += __shfl_xor(sum.x, msk); sum.y += __shfl_xor(sum.y, msk);
            sum.z += __shfl_xor(sum.z, msk); sum.w += __shfl_xor(sum.w, msk);
            mx.x = fmaxf(mx.x, __shfl_xor(mx.x, msk));
            mx.y = fmaxf(mx.y, __shfl_xor(mx.y, msk));
            mx.z = fmaxf(mx.z, __shfl_xor(mx.z, msk));
            mx.w = fmaxf(mx.w, __shfl_xor(mx.w, msk));
        }
        if (sub == 0) {
            float* ss = seg_sum + bfirst * INC + ch;
            atomicAdd(ss + 0, sum.x); atomicAdd(ss + 1, sum.y);
            atomicAdd(ss + 2, sum.z); atomicAdd(ss + 3, sum.w);
            float* sx = seg_max + bfirst * INC + ch;
            atomicMaxF(sx + 0, mx.x); atomicMaxF(sx + 1, mx.y);
            atomicMaxF(sx + 2, mx.z); atomicMaxF(sx + 3, mx.w);
            if (lane == 0) atomicAdd(&counts[bfirst], pend - start);
        }
        return;
    }

    // ---- slow path (<= 7 waves total): per-point batch tracking ----
    bool isCnt = (lane & 15) == 0;
    float4 sum = make_float4(0.f, 0.f, 0.f, 0.f);
    float4 mx  = make_float4(-INFINITY, -INFINITY, -INFINITY, -INFINITY);
    int cnt = 0, cur = -1;
    for (int p = start; p < pend; p += 4) {
        int pp = p + sub;
        int b = bidx[pp];
        if (b != cur) {
            if (cur >= 0) {
                float* ss = seg_sum + cur * INC + ch;
                atomicAdd(ss + 0, sum.x); atomicAdd(ss + 1, sum.y);
                atomicAdd(ss + 2, sum.z); atomicAdd(ss + 3, sum.w);
                float* sx = seg_max + cur * INC + ch;
                atomicMaxF(sx + 0, mx.x); atomicMaxF(sx + 1, mx.y);
                atomicMaxF(sx + 2, mx.z); atomicMaxF(sx + 3, mx.w);
                if (isCnt && cnt) atomicAdd(&counts[cur], cnt);
            }
            sum = make_float4(0.f, 0.f, 0.f, 0.f);
            mx  = make_float4(-INFINITY, -INFINITY, -INFINITY, -INFINITY);
            cnt = 0; cur = b;
        }
        const float4 v = *reinterpret_cast<const float4*>(F + (size_t)pp * INC + ch);
        acc4(sum, mx, v);
        cnt += (int)isCnt;
    }
    if (cur >= 0) {
        float* ss = seg_sum + cur * INC + ch;
        atomicAdd(ss + 0, sum.x); atomicAdd(ss + 1, sum.y);
        atomicAdd(ss + 2, sum.z); atomicAdd(ss + 3, sum.w);
        float* sx = seg_max + cur * INC + ch;
        atomicMaxF(sx + 0, mx.x); atomicMaxF(sx + 1, mx.y);
        atomicMaxF(sx + 2, mx.z); atomicMaxF(sx + 3, mx.w);
        if (isCnt && cnt) atomicAdd(&counts[cur], cnt);
    }
}

// -------- tiny per-batch MLP: gate[b][c] = sigmoid(mlp(avg)+mlp(mx)) ---------
__global__ void k_gate(const float* __restrict__ seg_sum, const float* __restrict__ seg_max,
                       const int* __restrict__ counts,
                       const float* __restrict__ W1, const float* __restrict__ b1,
                       const float* __restrict__ W2, const float* __restrict__ b2,
                       float* __restrict__ gate) {
    __shared__ float s_avg[NB * INC], s_mx[NB * INC];
    __shared__ float s_W1[INC * HID], s_W2[HID * INC];
    __shared__ float s_ha[NB * HID], s_hm[NB * HID];
    int t = threadIdx.x; // 512 threads
    s_W1[t] = W1[t]; s_W1[t + 512] = W1[t + 512];
    s_W2[t] = W2[t]; s_W2[t + 512] = W2[t + 512];
    {
        int b = t >> 6;
        float c = (float)counts[b];
        s_avg[t] = seg_sum[t] / c;
        s_mx[t]  = seg_max[t];
    }
    __syncthreads();
    if (t < NB * HID) {
        int b = t >> 4, j = t & (HID - 1);
        float ha = b1[j], hm = b1[j];
        #pragma unroll
        for (int c = 0; c < INC; ++c) {
            float w = s_W1[c * HID + j];
            ha += s_avg[b * INC + c] * w;
            hm += s_mx[b * INC + c] * w;
        }
        s_ha[t] = fmaxf(ha, 0.f);
        s_hm[t] = fmaxf(hm, 0.f);
    }
    __syncthreads();
    {
        int b = t >> 6, c = t & 63;
        float o = 2.f * b2[c];
        #pragma unroll
        for (int j = 0; j < HID; ++j)
            o += (s_ha[b * HID + j] + s_hm[b * HID + j]) * W2[j * INC + c];
        gate[t] = 1.f / (1.f + expf(-o));
    }
}

// ------- per-point channel mean/max of z = F*gate -> sm[N][2] ---------------
// chunked like k_reduce; uniform-batch fast path loads the gate row ONCE.
__global__ void k_sm(const float* __restrict__ F, const int* __restrict__ bidx,
                     const float* __restrict__ gate, float* __restrict__ sm,
                     int N, int CHUNK) {
    int lane = threadIdx.x & 63;
    int wave = (blockIdx.x * blockDim.x + threadIdx.x) >> 6;
    int start = wave * CHUNK;
    if (start >= N) return;
    int pend = min(start + CHUNK, N);
    int sub = lane >> 4, ch = (lane & 15) << 2;
    bool wr = (lane & 15) == 0;

    int bfirst = bidx[start];
    int blast  = bidx[pend - 1];

    if (bfirst == blast) {
        const float4 g = *reinterpret_cast<const float4*>(gate + bfirst * INC + ch);
        const float* fb = F + (size_t)sub * INC + ch;
        int p = start;
        for (; p + 16 <= pend; p += 16) {
            const float* fp = fb + (size_t)p * INC;
            float4 v0 = *reinterpret_cast<const float4*>(fp);
            float4 v1 = *reinterpret_cast<const float4*>(fp + 4 * INC);
            float4 v2 = *reinterpret_cast<const float4*>(fp + 8 * INC);
            float4 v3 = *reinterpret_cast<const float4*>(fp + 12 * INC);
            float s0, s1, s2, s3, m0, m1, m2, m3;
            {
                float4 z = make_float4(v0.x*g.x, v0.y*g.y, v0.z*g.z, v0.w*g.w);
                s0 = z.x + z.y + z.z + z.w; m0 = fmaxf(fmaxf(z.x, z.y), fmaxf(z.z, z.w));
            }
            {
                float4 z = make_float4(v1.x*g.x, v1.y*g.y, v1.z*g.z, v1.w*g.w);
                s1 = z.x + z.y + z.z + z.w; m1 = fmaxf(fmaxf(z.x, z.y), fmaxf(z.z, z.w));
            }
            {
                float4 z = make_float4(v2.x*g.x, v2.y*g.y, v2.z*g.z, v2.w*g.w);
                s2 = z.x + z.y + z.z + z.w; m2 = fmaxf(fmaxf(z.x, z.y), fmaxf(z.z, z.w));
            }
            {
                float4 z = make_float4(v3.x*g.x, v3.y*g.y, v3.z*g.z, v3.w*g.w);
                s3 = z.x + z.y + z.z + z.w; m3 = fmaxf(fmaxf(z.x, z.y), fmaxf(z.z, z.w));
            }
            #pragma unroll
            for (int msk = 1; msk < 16; msk <<= 1) {
                s0 += __shfl_xor(s0, msk); m0 = fmaxf(m0, __shfl_xor(m0, msk));
                s1 += __shfl_xor(s1, msk); m1 = fmaxf(m1, __shfl_xor(m1, msk));
                s2 += __shfl_xor(s2, msk); m2 = fmaxf(m2, __shfl_xor(m2, msk));
                s3 += __shfl_xor(s3, msk); m3 = fmaxf(m3, __shfl_xor(m3, msk));
            }
            if (wr) {
                *reinterpret_cast<float2*>(sm + (size_t)(p + sub) * 2)      = make_float2(s0 * (1.f/64.f), m0);
                *reinterpret_cast<float2*>(sm + (size_t)(p + 4 + sub) * 2)  = make_float2(s1 * (1.f/64.f), m1);
                *reinterpret_cast<float2*>(sm + (size_t)(p + 8 + sub) * 2)  = make_float2(s2 * (1.f/64.f), m2);
                *reinterpret_cast<float2*>(sm + (size_t)(p + 12 + sub) * 2) = make_float2(s3 * (1.f/64.f), m3);
            }
        }
        for (; p < pend; p += 4) {
            float4 v = *reinterpret_cast<const float4*>(fb + (size_t)p * INC);
            float4 z = make_float4(v.x*g.x, v.y*g.y, v.z*g.z, v.w*g.w);
            float s = z.x + z.y + z.z + z.w;
            float m = fmaxf(fmaxf(z.x, z.y), fmaxf(z.z, z.w));
            #pragma unroll
            for (int msk = 1; msk < 16; msk <<= 1) {
                s += __shfl_xor(s, msk); m = fmaxf(m, __shfl_xor(m, msk));
            }
            if (wr) *reinterpret_cast<float2*>(sm + (size_t)(p + sub) * 2) = make_float2(s * (1.f/64.f), m);
        }
        return;
    }

    // slow path (<=7 waves): per-point gate gather
    for (int p = start; p < pend; p += 4) {
        int pp = p + sub;
        int b = bidx[pp];
        float4 v = *reinterpret_cast<const float4*>(F + (size_t)pp * INC + ch);
        float4 g = *reinterpret_cast<const float4*>(gate + b * INC + ch);
        float4 z = make_float4(v.x*g.x, v.y*g.y, v.z*g.z, v.w*g.w);
        float s = z.x + z.y + z.z + z.w;
        float m = fmaxf(fmaxf(z.x, z.y), fmaxf(z.z, z.w));
        #pragma unroll
        for (int msk = 1; msk < 16; msk <<= 1) {
            s += __shfl_xor(s, msk); m = fmaxf(m, __shfl_xor(m, msk));
        }
        if (wr) *reinterpret_cast<float2*>(sm + (size_t)pp * 2) = make_float2(s * (1.f/64.f), m);
    }
}

// ------- gather 27 neighbors' sm, 2ch conv, final out = z * sigmoid(c) ------
// chunked; fast path has gate row in register + software-pipelined nbr loads.
__global__ void k_out(const float* __restrict__ F, const int* __restrict__ bidx,
                      const int* __restrict__ nbr, const float* __restrict__ gate,
                      const float* __restrict__ sm, const float* __restrict__ cw,
                      float* __restrict__ out, int N, int CHUNK) {
    int lane = threadIdx.x & 63;
    int j = lane & 15;
    int sub = lane >> 4, ch = (lane & 15) << 2;
    float2 cwa = make_float2(cw[2 * j], cw[2 * j + 1]);
    float2 cwb = (j < 11) ? make_float2(cw[2 * (16 + j)], cw[2 * (16 + j) + 1])
                          : make_float2(0.f, 0.f);
    int wave = (blockIdx.x * blockDim.x + threadIdx.x) >> 6;
    int start = wave * CHUNK;
    if (start >= N) return;
    int pend = min(start + CHUNK, N);

    int bfirst = bidx[start];
    int blast  = bidx[pend - 1];

    if (bfirst == blast) {
        const float4 g = *reinterpret_cast<const float4*>(gate + bfirst * INC + ch);
        // pipeline prologue: indices for first group
        int pp = start + sub;
        int i1 = nbr[pp * 27 + j];
        int i2 = (j < 11) ? nbr[pp * 27 + 16 + j] : N;
        for (int p = start; p < pend; p += 4) {
            // issue sm gathers for current group
            float2 a = *reinterpret_cast<const float2*>(sm + (size_t)i1 * 2);
            float2 b = *reinterpret_cast<const float2*>(sm + (size_t)i2 * 2);
            // prefetch next group's indices (independent of gathers)
            int np = p + 4 + sub; if (np >= N) np = N - 1;
            int ni1 = nbr[np * 27 + j];
            int ni2 = (j < 11) ? nbr[np * 27 + 16 + j] : N;
            // F load for current group (independent)
            float4 v = *reinterpret_cast<const float4*>(F + (size_t)(p + sub) * INC + ch);
            float cpart = a.x * cwa.x + a.y * cwa.y + b.x * cwb.x + b.y * cwb.y;
            #pragma unroll
            for (int msk = 1; msk < 16; msk <<= 1) cpart += __shfl_xor(cpart, msk);
            float sig = 1.f / (1.f + expf(-cpart));
            float4 o = make_float4(v.x * g.x * sig, v.y * g.y * sig,
                                   v.z * g.z * sig, v.w * g.w * sig);
            *reinterpret_cast<float4*>(out + (size_t)(p + sub) * INC + ch) = o;
            i1 = ni1; i2 = ni2;
        }
        return;
    }

    // slow path (<=7 waves): per-point bidx + gate gather
    for (int p = start; p < pend; p += 4) {
        int pp = p + sub;
        int rb = pp * 27;
        int i1 = nbr[rb + j];
        int i2 = (j < 11) ? nbr[rb + 16 + j] : N;
        float2 a = *reinterpret_cast<const float2*>(sm + (size_t)i1 * 2);
        float2 b = *reinterpret_cast<const float2*>(sm + (size_t)i2 * 2);
        float cpart = a.x * cwa.x + a.y * cwa.y + b.x * cwb.x + b.y * cwb.y;
        #pragma unroll
        for (int msk = 1; msk < 16; msk <<= 1) cpart += __shfl_xor(cpart, msk);
        float sig = 1.f / (1.f + expf(-cpart));
        int bb = bidx[pp];
        float4 v = *reinterpret_cast<const float4*>(F + (size_t)pp * INC + ch);
        float4 g = *reinterpret_cast<const float4*>(gate + bb * INC + ch);
        float4 o = make_float4(v.x * g.x * sig, v.y * g.y * sig,
                               v.z * g.z * sig, v.w * g.w * sig);
        *reinterpret_cast<float4*>(out + (size_t)pp * INC + ch) = o;
    }
}

extern "C" void kernel_launch(void* const* d_in, const int* in_sizes, int n_in,
                              void* d_out, int out_size, void* d_ws, size_t ws_size,
                              hipStream_t stream) {
    const float* F    = (const float*)d_in[0];
    const int*   bidx = (const int*)d_in[1];
    const int*   nbr  = (const int*)d_in[2];
    const float* W1   = (const float*)d_in[3];
    const float* b1   = (const float*)d_in[4];
    const float* W2   = (const float*)d_in[5];
    const float* b2   = (const float*)d_in[6];
    const float* cw   = (const float*)d_in[7];
    float* out = (float*)d_out;
    int N = in_sizes[1];

    float* ws      = (float*)d_ws;
    float* seg_sum = ws;                 // 512
    float* seg_max = ws + NB * INC;      // 512
    int*   counts  = (int*)(ws + 2 * NB * INC); // 8
    float* gate    = ws + 2 * NB * INC + 16;    // 512
    float* sm      = ws + 3 * NB * INC + 32;    // (N+1)*2, 8B-aligned

    k_init<<<1, 1024, 0, stream>>>(seg_sum, seg_max, counts, sm + (size_t)N * 2);

    // k_reduce: 1024 blocks x 256 thr = 4096 waves, chunk multiple of 16
    {
        const int waves = 4096;
        int chunk = ((N + waves * 16 - 1) / (waves * 16)) * 16;
        k_reduce<<<1024, 256, 0, stream>>>(F, bidx, seg_sum, seg_max, counts, N, chunk);
    }

    k_gate<<<1, 512, 0, stream>>>(seg_sum, seg_max, counts, W1, b1, W2, b2, gate);

    // k_sm / k_out: 2048 blocks x 256 thr = 8192 waves
    {
        const int waves = 8192;
        int chunk = ((N + waves * 16 - 1) / (waves * 16)) * 16;
        k_sm<<<2048, 256, 0, stream>>>(F, bidx, gate, sm, N, chunk);
        k_out<<<2048, 256, 0, stream>>>(F, bidx, nbr, gate, sm, cw, out, N, chunk);
    }
}

// Round 5
// 250.920 us; speedup vs baseline: 1.1399x; 1.1399x over previous
//
#include <hip/hip_runtime.h>
#include <math.h>

#define INC 64
#define HID 16
#define NB 8

__device__ __forceinline__ void atomicMaxF(float* addr, float val) {
    // float-max-via-int trick: valid for mixed signs, target initialized to -inf
    if (val >= 0.0f) atomicMax((int*)addr, __float_as_int(val));
    else             atomicMin((unsigned int*)addr, __float_as_uint(val));
}

__device__ __forceinline__ void acc4(float4& sum, float4& mx, const float4 v) {
    sum.x += v.x; sum.y += v.y; sum.z += v.z; sum.w += v.w;
    mx.x = fmaxf(mx.x, v.x); mx.y = fmaxf(mx.y, v.y);
    mx.z = fmaxf(mx.z, v.z); mx.w = fmaxf(mx.w, v.w);
}

// ---------------- init workspace (ws is poisoned 0xAA before every launch) ---
__global__ void k_init(float* seg_sum, float* seg_max, int* counts, float* sm_pad) {
    int t = threadIdx.x;
    if (t < NB * INC) { seg_sum[t] = 0.0f; seg_max[t] = -INFINITY; }
    else if (t < NB * INC + NB) counts[t - NB * INC] = 0;
    else if (t < NB * INC + NB + 2) sm_pad[t - NB * INC - NB] = 0.0f; // pad row N
}

// ------------- segmented sum/max/count over sorted batch_idx -----------------
// Block owns 4*CHUNK contiguous points (wave w: [start, start+CHUNK)).
// Lane L: sub = L>>4 (point within group of 4), ch = (L&15)*4.
// Block-uniform batch (all but <=7 blocks): LDS-combine 4 waves -> ONE atomic
// set per block. Fast stream = 4 independent float4 loads pinned ahead of
// VALU by sched_barrier(0) so 4 loads stay in flight.
__global__ void k_reduce(const float* __restrict__ F, const int* __restrict__ bidx,
                         float* __restrict__ seg_sum, float* __restrict__ seg_max,
                         int* __restrict__ counts, int N, int CHUNK) {
    __shared__ float4 lsum[4][16];
    __shared__ float4 lmax[4][16];

    int lane = threadIdx.x & 63;
    int wid  = threadIdx.x >> 6;          // wave in block, 0..3
    int blockStart = blockIdx.x * (CHUNK * 4);
    if (blockStart >= N) return;
    int blockEnd = min(blockStart + CHUNK * 4, N);
    int start = blockStart + wid * CHUNK;
    bool active = start < N;
    int pend = active ? min(start + CHUNK, N) : start;

    int sub = lane >> 4;
    int ch  = (lane & 15) << 2;

    int bblk = bidx[blockStart];
    bool blockUniform = (bidx[blockEnd - 1] == bblk);

    if (blockUniform) {
        float4 s0 = make_float4(0.f,0.f,0.f,0.f), s1 = s0, s2 = s0, s3 = s0;
        float4 m0 = make_float4(-INFINITY,-INFINITY,-INFINITY,-INFINITY);
        float4 m1 = m0, m2 = m0, m3 = m0;
        if (active) {
            const float* fb = F + (size_t)sub * INC + ch;
            int p = start;
            #pragma unroll 1
            for (; p + 16 <= pend; p += 16) {
                const float* fp = fb + (size_t)p * INC;
                float4 v0 = *reinterpret_cast<const float4*>(fp);
                float4 v1 = *reinterpret_cast<const float4*>(fp + 4 * INC);
                float4 v2 = *reinterpret_cast<const float4*>(fp + 8 * INC);
                float4 v3 = *reinterpret_cast<const float4*>(fp + 12 * INC);
                __builtin_amdgcn_sched_barrier(0);
                acc4(s0, m0, v0); acc4(s1, m1, v1);
                acc4(s2, m2, v2); acc4(s3, m3, v3);
            }
            #pragma unroll 1
            for (; p < pend; p += 4) {
                float4 v = *reinterpret_cast<const float4*>(fb + (size_t)p * INC);
                acc4(s0, m0, v);
            }
        }
        // merge 4 streams
        s0.x += s1.x + s2.x + s3.x; s0.y += s1.y + s2.y + s3.y;
        s0.z += s1.z + s2.z + s3.z; s0.w += s1.w + s2.w + s3.w;
        m0.x = fmaxf(fmaxf(m0.x, m1.x), fmaxf(m2.x, m3.x));
        m0.y = fmaxf(fmaxf(m0.y, m1.y), fmaxf(m2.y, m3.y));
        m0.z = fmaxf(fmaxf(m0.z, m1.z), fmaxf(m2.z, m3.z));
        m0.w = fmaxf(fmaxf(m0.w, m1.w), fmaxf(m2.w, m3.w));
        // combine the 4 sub-copies (lanes differing in bits 4,5)
        #pragma unroll
        for (int msk = 16; msk < 64; msk <<= 1) {
            s0.x += __shfl_xor(s0.x, msk); s0.y += __shfl_xor(s0.y, msk);
            s0.z += __shfl_xor(s0.z, msk); s0.w += __shfl_xor(s0.w, msk);
            m0.x = fmaxf(m0.x, __shfl_xor(m0.x, msk));
            m0.y = fmaxf(m0.y, __shfl_xor(m0.y, msk));
            m0.z = fmaxf(m0.z, __shfl_xor(m0.z, msk));
            m0.w = fmaxf(m0.w, __shfl_xor(m0.w, msk));
        }
        if (lane < 16) { lsum[wid][lane] = s0; lmax[wid][lane] = m0; }
        __syncthreads();
        if (wid == 0 && lane < 16) {
            float4 a0 = lsum[0][lane], a1 = lsum[1][lane], a2 = lsum[2][lane], a3 = lsum[3][lane];
            float4 x0 = lmax[0][lane], x1 = lmax[1][lane], x2 = lmax[2][lane], x3 = lmax[3][lane];
            float4 S = make_float4(a0.x+a1.x+a2.x+a3.x, a0.y+a1.y+a2.y+a3.y,
                                   a0.z+a1.z+a2.z+a3.z, a0.w+a1.w+a2.w+a3.w);
            float4 M = make_float4(fmaxf(fmaxf(x0.x,x1.x),fmaxf(x2.x,x3.x)),
                                   fmaxf(fmaxf(x0.y,x1.y),fmaxf(x2.y,x3.y)),
                                   fmaxf(fmaxf(x0.z,x1.z),fmaxf(x2.z,x3.z)),
                                   fmaxf(fmaxf(x0.w,x1.w),fmaxf(x2.w,x3.w)));
            float* ss = seg_sum + bblk * INC + (lane << 2);
            atomicAdd(ss + 0, S.x); atomicAdd(ss + 1, S.y);
            atomicAdd(ss + 2, S.z); atomicAdd(ss + 3, S.w);
            float* sx = seg_max + bblk * INC + (lane << 2);
            atomicMaxF(sx + 0, M.x); atomicMaxF(sx + 1, M.y);
            atomicMaxF(sx + 2, M.z); atomicMaxF(sx + 3, M.w);
            if (lane == 0) atomicAdd(&counts[bblk], blockEnd - blockStart);
        }
        return;
    }

    // ---- non-uniform block (<=7 per launch): per-wave handling ----
    if (!active) return;
    int bfirst = bidx[start];
    int blast  = bidx[pend - 1];

    if (bfirst == blast) {
        float4 sum = make_float4(0.f,0.f,0.f,0.f);
        float4 mx  = make_float4(-INFINITY,-INFINITY,-INFINITY,-INFINITY);
        const float* fb = F + (size_t)sub * INC + ch;
        #pragma unroll 1
        for (int p = start; p < pend; p += 4) {
            float4 v = *reinterpret_cast<const float4*>(fb + (size_t)p * INC);
            acc4(sum, mx, v);
        }
        #pragma unroll
        for (int msk = 16; msk < 64; msk <<= 1) {
            sum.x += __shfl_xor(sum.x, msk); sum.y += __shfl_xor(sum.y, msk);
            sum.z += __shfl_xor(sum.z, msk); sum.w += __shfl_xor(sum.w, msk);
            mx.x = fmaxf(mx.x, __shfl_xor(mx.x, msk));
            mx.y = fmaxf(mx.y, __shfl_xor(mx.y, msk));
            mx.z = fmaxf(mx.z, __shfl_xor(mx.z, msk));
            mx.w = fmaxf(mx.w, __shfl_xor(mx.w, msk));
        }
        if (sub == 0) {
            float* ss = seg_sum + bfirst * INC + ch;
            atomicAdd(ss + 0, sum.x); atomicAdd(ss + 1, sum.y);
            atomicAdd(ss + 2, sum.z); atomicAdd(ss + 3, sum.w);
            float* sx = seg_max + bfirst * INC + ch;
            atomicMaxF(sx + 0, mx.x); atomicMaxF(sx + 1, mx.y);
            atomicMaxF(sx + 2, mx.z); atomicMaxF(sx + 3, mx.w);
            if (lane == 0) atomicAdd(&counts[bfirst], pend - start);
        }
        return;
    }

    bool isCnt = (lane & 15) == 0;
    float4 sum = make_float4(0.f,0.f,0.f,0.f);
    float4 mx  = make_float4(-INFINITY,-INFINITY,-INFINITY,-INFINITY);
    int cnt = 0, cur = -1;
    for (int p = start; p < pend; p += 4) {
        int pp = p + sub;
        int b = bidx[pp];
        if (b != cur) {
            if (cur >= 0) {
                float* ss = seg_sum + cur * INC + ch;
                atomicAdd(ss + 0, sum.x); atomicAdd(ss + 1, sum.y);
                atomicAdd(ss + 2, sum.z); atomicAdd(ss + 3, sum.w);
                float* sx = seg_max + cur * INC + ch;
                atomicMaxF(sx + 0, mx.x); atomicMaxF(sx + 1, mx.y);
                atomicMaxF(sx + 2, mx.z); atomicMaxF(sx + 3, mx.w);
                if (isCnt && cnt) atomicAdd(&counts[cur], cnt);
            }
            sum = make_float4(0.f,0.f,0.f,0.f);
            mx  = make_float4(-INFINITY,-INFINITY,-INFINITY,-INFINITY);
            cnt = 0; cur = b;
        }
        const float4 v = *reinterpret_cast<const float4*>(F + (size_t)pp * INC + ch);
        acc4(sum, mx, v);
        cnt += (int)isCnt;
    }
    if (cur >= 0) {
        float* ss = seg_sum + cur * INC + ch;
        atomicAdd(ss + 0, sum.x); atomicAdd(ss + 1, sum.y);
        atomicAdd(ss + 2, sum.z); atomicAdd(ss + 3, sum.w);
        float* sx = seg_max + cur * INC + ch;
        atomicMaxF(sx + 0, mx.x); atomicMaxF(sx + 1, mx.y);
        atomicMaxF(sx + 2, mx.z); atomicMaxF(sx + 3, mx.w);
        if (isCnt && cnt) atomicAdd(&counts[cur], cnt);
    }
}

// -------- tiny per-batch MLP: gate[b][c] = sigmoid(mlp(avg)+mlp(mx)) ---------
__global__ void k_gate(const float* __restrict__ seg_sum, const float* __restrict__ seg_max,
                       const int* __restrict__ counts,
                       const float* __restrict__ W1, const float* __restrict__ b1,
                       const float* __restrict__ W2, const float* __restrict__ b2,
                       float* __restrict__ gate) {
    __shared__ float s_avg[NB * INC], s_mx[NB * INC];
    __shared__ float s_W1[INC * HID], s_W2[HID * INC];
    __shared__ float s_ha[NB * HID], s_hm[NB * HID];
    int t = threadIdx.x; // 512 threads
    s_W1[t] = W1[t]; s_W1[t + 512] = W1[t + 512];
    s_W2[t] = W2[t]; s_W2[t + 512] = W2[t + 512];
    {
        int b = t >> 6;
        float c = (float)counts[b];
        s_avg[t] = seg_sum[t] / c;
        s_mx[t]  = seg_max[t];
    }
    __syncthreads();
    if (t < NB * HID) {
        int b = t >> 4, j = t & (HID - 1);
        float ha = b1[j], hm = b1[j];
        #pragma unroll
        for (int c = 0; c < INC; ++c) {
            float w = s_W1[c * HID + j];
            ha += s_avg[b * INC + c] * w;
            hm += s_mx[b * INC + c] * w;
        }
        s_ha[t] = fmaxf(ha, 0.f);
        s_hm[t] = fmaxf(hm, 0.f);
    }
    __syncthreads();
    {
        int b = t >> 6, c = t & 63;
        float o = 2.f * b2[c];
        #pragma unroll
        for (int j = 0; j < HID; ++j)
            o += (s_ha[b * HID + j] + s_hm[b * HID + j]) * s_W2[j * INC + c];
        gate[t] = 1.f / (1.f + expf(-o));
    }
}

// ------- per-point channel mean/max of z = F*gate -> sm[N][2] ---------------
__global__ void k_sm(const float* __restrict__ F, const int* __restrict__ bidx,
                     const float* __restrict__ gate, float* __restrict__ sm,
                     int N, int CHUNK) {
    int lane = threadIdx.x & 63;
    int wave = (blockIdx.x * blockDim.x + threadIdx.x) >> 6;
    int start = wave * CHUNK;
    if (start >= N) return;
    int pend = min(start + CHUNK, N);
    int sub = lane >> 4, ch = (lane & 15) << 2;
    bool wr = (lane & 15) == 0;

    int bfirst = bidx[start];
    int blast  = bidx[pend - 1];

    if (bfirst == blast) {
        const float4 g = *reinterpret_cast<const float4*>(gate + bfirst * INC + ch);
        const float* fb = F + (size_t)sub * INC + ch;
        int p = start;
        #pragma unroll 1
        for (; p + 16 <= pend; p += 16) {
            const float* fp = fb + (size_t)p * INC;
            float4 v0 = *reinterpret_cast<const float4*>(fp);
            float4 v1 = *reinterpret_cast<const float4*>(fp + 4 * INC);
            float4 v2 = *reinterpret_cast<const float4*>(fp + 8 * INC);
            float4 v3 = *reinterpret_cast<const float4*>(fp + 12 * INC);
            __builtin_amdgcn_sched_barrier(0);
            float s0, s1, s2, s3, m0, m1, m2, m3;
            {
                float4 z = make_float4(v0.x*g.x, v0.y*g.y, v0.z*g.z, v0.w*g.w);
                s0 = z.x + z.y + z.z + z.w; m0 = fmaxf(fmaxf(z.x, z.y), fmaxf(z.z, z.w));
            }
            {
                float4 z = make_float4(v1.x*g.x, v1.y*g.y, v1.z*g.z, v1.w*g.w);
                s1 = z.x + z.y + z.z + z.w; m1 = fmaxf(fmaxf(z.x, z.y), fmaxf(z.z, z.w));
            }
            {
                float4 z = make_float4(v2.x*g.x, v2.y*g.y, v2.z*g.z, v2.w*g.w);
                s2 = z.x + z.y + z.z + z.w; m2 = fmaxf(fmaxf(z.x, z.y), fmaxf(z.z, z.w));
            }
            {
                float4 z = make_float4(v3.x*g.x, v3.y*g.y, v3.z*g.z, v3.w*g.w);
                s3 = z.x + z.y + z.z + z.w; m3 = fmaxf(fmaxf(z.x, z.y), fmaxf(z.z, z.w));
            }
            #pragma unroll
            for (int msk = 1; msk < 16; msk <<= 1) {
                s0 += __shfl_xor(s0, msk); m0 = fmaxf(m0, __shfl_xor(m0, msk));
                s1 += __shfl_xor(s1, msk); m1 = fmaxf(m1, __shfl_xor(m1, msk));
                s2 += __shfl_xor(s2, msk); m2 = fmaxf(m2, __shfl_xor(m2, msk));
                s3 += __shfl_xor(s3, msk); m3 = fmaxf(m3, __shfl_xor(m3, msk));
            }
            if (wr) {
                *reinterpret_cast<float2*>(sm + (size_t)(p + sub) * 2)      = make_float2(s0 * (1.f/64.f), m0);
                *reinterpret_cast<float2*>(sm + (size_t)(p + 4 + sub) * 2)  = make_float2(s1 * (1.f/64.f), m1);
                *reinterpret_cast<float2*>(sm + (size_t)(p + 8 + sub) * 2)  = make_float2(s2 * (1.f/64.f), m2);
                *reinterpret_cast<float2*>(sm + (size_t)(p + 12 + sub) * 2) = make_float2(s3 * (1.f/64.f), m3);
            }
        }
        #pragma unroll 1
        for (; p < pend; p += 4) {
            float4 v = *reinterpret_cast<const float4*>(fb + (size_t)p * INC);
            float4 z = make_float4(v.x*g.x, v.y*g.y, v.z*g.z, v.w*g.w);
            float s = z.x + z.y + z.z + z.w;
            float m = fmaxf(fmaxf(z.x, z.y), fmaxf(z.z, z.w));
            #pragma unroll
            for (int msk = 1; msk < 16; msk <<= 1) {
                s += __shfl_xor(s, msk); m = fmaxf(m, __shfl_xor(m, msk));
            }
            if (wr) *reinterpret_cast<float2*>(sm + (size_t)(p + sub) * 2) = make_float2(s * (1.f/64.f), m);
        }
        return;
    }

    // slow path (<=7 waves): per-point gate gather
    for (int p = start; p < pend; p += 4) {
        int pp = p + sub;
        int b = bidx[pp];
        float4 v = *reinterpret_cast<const float4*>(F + (size_t)pp * INC + ch);
        float4 g = *reinterpret_cast<const float4*>(gate + b * INC + ch);
        float4 z = make_float4(v.x*g.x, v.y*g.y, v.z*g.z, v.w*g.w);
        float s = z.x + z.y + z.z + z.w;
        float m = fmaxf(fmaxf(z.x, z.y), fmaxf(z.z, z.w));
        #pragma unroll
        for (int msk = 1; msk < 16; msk <<= 1) {
            s += __shfl_xor(s, msk); m = fmaxf(m, __shfl_xor(m, msk));
        }
        if (wr) *reinterpret_cast<float2*>(sm + (size_t)pp * 2) = make_float2(s * (1.f/64.f), m);
    }
}

// ------- gather 27 neighbors' sm, 2ch conv, final out = z * sigmoid(c) ------
__global__ void k_out(const float* __restrict__ F, const int* __restrict__ bidx,
                      const int* __restrict__ nbr, const float* __restrict__ gate,
                      const float* __restrict__ sm, const float* __restrict__ cw,
                      float* __restrict__ out, int N, int CHUNK) {
    int lane = threadIdx.x & 63;
    int j = lane & 15;
    int sub = lane >> 4, ch = (lane & 15) << 2;
    float2 cwa = make_float2(cw[2 * j], cw[2 * j + 1]);
    float2 cwb = (j < 11) ? make_float2(cw[2 * (16 + j)], cw[2 * (16 + j) + 1])
                          : make_float2(0.f, 0.f);
    int wave = (blockIdx.x * blockDim.x + threadIdx.x) >> 6;
    int start = wave * CHUNK;
    if (start >= N) return;
    int pend = min(start + CHUNK, N);

    int bfirst = bidx[start];
    int blast  = bidx[pend - 1];

    if (bfirst == blast) {
        const float4 g = *reinterpret_cast<const float4*>(gate + bfirst * INC + ch);
        int pp = start + sub;
        int i1 = nbr[pp * 27 + j];
        int i2 = (j < 11) ? nbr[pp * 27 + 16 + j] : N;
        #pragma unroll 1
        for (int p = start; p < pend; p += 4) {
            // current group's gathers + next group's indices + F, all in flight
            float2 a = *reinterpret_cast<const float2*>(sm + (size_t)i1 * 2);
            float2 b = *reinterpret_cast<const float2*>(sm + (size_t)i2 * 2);
            int np = p + 4 + sub; if (np >= N) np = N - 1;
            int ni1 = nbr[np * 27 + j];
            int ni2 = (j < 11) ? nbr[np * 27 + 16 + j] : N;
            float4 v = *reinterpret_cast<const float4*>(F + (size_t)(p + sub) * INC + ch);
            __builtin_amdgcn_sched_barrier(0);
            float cpart = a.x * cwa.x + a.y * cwa.y + b.x * cwb.x + b.y * cwb.y;
            #pragma unroll
            for (int msk = 1; msk < 16; msk <<= 1) cpart += __shfl_xor(cpart, msk);
            float sig = 1.f / (1.f + expf(-cpart));
            float4 o = make_float4(v.x * g.x * sig, v.y * g.y * sig,
                                   v.z * g.z * sig, v.w * g.w * sig);
            *reinterpret_cast<float4*>(out + (size_t)(p + sub) * INC + ch) = o;
            i1 = ni1; i2 = ni2;
        }
        return;
    }

    // slow path (<=7 waves): per-point bidx + gate gather
    for (int p = start; p < pend; p += 4) {
        int pp = p + sub;
        int rb = pp * 27;
        int i1 = nbr[rb + j];
        int i2 = (j < 11) ? nbr[rb + 16 + j] : N;
        float2 a = *reinterpret_cast<const float2*>(sm + (size_t)i1 * 2);
        float2 b = *reinterpret_cast<const float2*>(sm + (size_t)i2 * 2);
        float cpart = a.x * cwa.x + a.y * cwa.y + b.x * cwb.x + b.y * cwb.y;
        #pragma unroll
        for (int msk = 1; msk < 16; msk <<= 1) cpart += __shfl_xor(cpart, msk);
        float sig = 1.f / (1.f + expf(-cpart));
        int bb = bidx[pp];
        float4 v = *reinterpret_cast<const float4*>(F + (size_t)pp * INC + ch);
        float4 g = *reinterpret_cast<const float4*>(gate + bb * INC + ch);
        float4 o = make_float4(v.x * g.x * sig, v.y * g.y * sig,
                               v.z * g.z * sig, v.w * g.w * sig);
        *reinterpret_cast<float4*>(out + (size_t)pp * INC + ch) = o;
    }
}

extern "C" void kernel_launch(void* const* d_in, const int* in_sizes, int n_in,
                              void* d_out, int out_size, void* d_ws, size_t ws_size,
                              hipStream_t stream) {
    const float* F    = (const float*)d_in[0];
    const int*   bidx = (const int*)d_in[1];
    const int*   nbr  = (const int*)d_in[2];
    const float* W1   = (const float*)d_in[3];
    const float* b1   = (const float*)d_in[4];
    const float* W2   = (const float*)d_in[5];
    const float* b2   = (const float*)d_in[6];
    const float* cw   = (const float*)d_in[7];
    float* out = (float*)d_out;
    int N = in_sizes[1];

    float* ws      = (float*)d_ws;
    float* seg_sum = ws;                 // 512
    float* seg_max = ws + NB * INC;      // 512
    int*   counts  = (int*)(ws + 2 * NB * INC); // 8
    float* gate    = ws + 2 * NB * INC + 16;    // 512
    float* sm      = ws + 3 * NB * INC + 32;    // (N+1)*2, 8B-aligned

    k_init<<<1, 1024, 0, stream>>>(seg_sum, seg_max, counts, sm + (size_t)N * 2);

    // k_reduce: ~2048 waves; chunk per wave multiple of 16; block owns 4*chunk
    {
        const int waves = 2048;
        int chunk = ((N + waves * 16 - 1) / (waves * 16)) * 16;   // 160 for N=300k
        int blocks = (N + chunk * 4 - 1) / (chunk * 4);
        k_reduce<<<blocks, 256, 0, stream>>>(F, bidx, seg_sum, seg_max, counts, N, chunk);
    }

    k_gate<<<1, 512, 0, stream>>>(seg_sum, seg_max, counts, W1, b1, W2, b2, gate);

    // k_sm / k_out: ~4096 waves, chunk multiple of 16
    {
        const int waves = 4096;
        int chunk = ((N + waves * 16 - 1) / (waves * 16)) * 16;   // 80 for N=300k
        int blocks = (N + chunk * 4 - 1) / (chunk * 4);
        k_sm<<<blocks, 256, 0, stream>>>(F, bidx, gate, sm, N, chunk);
        k_out<<<blocks, 256, 0, stream>>>(F, bidx, nbr, gate, sm, cw, out, N, chunk);
    }
}

// Round 6
// 233.138 us; speedup vs baseline: 1.2268x; 1.0763x over previous
//
#include <hip/hip_runtime.h>
#include <math.h>

#define INC 64
#define HID 16
#define NB 8

__device__ __forceinline__ void atomicMaxF(float* addr, float val) {
    // float-max-via-int trick: valid for mixed signs, target initialized to -inf
    if (val >= 0.0f) atomicMax((int*)addr, __float_as_int(val));
    else             atomicMin((unsigned int*)addr, __float_as_uint(val));
}

__device__ __forceinline__ void acc4(float4& sum, float4& mx, const float4 v) {
    sum.x += v.x; sum.y += v.y; sum.z += v.z; sum.w += v.w;
    mx.x = fmaxf(mx.x, v.x); mx.y = fmaxf(mx.y, v.y);
    mx.z = fmaxf(mx.z, v.z); mx.w = fmaxf(mx.w, v.w);
}

// ---------------- init workspace (ws is poisoned 0xAA before every launch) ---
__global__ void k_init(float* seg_sum, float* seg_max, int* counts, float* sm_pad) {
    int t = threadIdx.x;
    if (t < NB * INC) { seg_sum[t] = 0.0f; seg_max[t] = -INFINITY; }
    else if (t < NB * INC + NB) counts[t - NB * INC] = 0;
    else if (t < NB * INC + NB + 2) sm_pad[t - NB * INC - NB] = 0.0f; // pad row N
}

// ------------- segmented sum/max/count over sorted batch_idx -----------------
// 1024-thread blocks = 16 waves; block span = 16*CHUNK contiguous points.
// Uniform block (all but <=7): 4-stream pinned loads, shuffle + LDS combine,
// ONE atomic set per block. Lane L: sub = L>>4, ch = (L&15)*4.
__global__ __launch_bounds__(1024)
void k_reduce(const float* __restrict__ F, const int* __restrict__ bidx,
              float* __restrict__ seg_sum, float* __restrict__ seg_max,
              int* __restrict__ counts, int N, int CHUNK) {
    __shared__ float4 lsum[16][16];
    __shared__ float4 lmax[16][16];

    int lane = threadIdx.x & 63;
    int wid  = threadIdx.x >> 6;          // wave in block, 0..15
    int blockStart = blockIdx.x * (CHUNK * 16);
    if (blockStart >= N) return;
    int blockEnd = min(blockStart + CHUNK * 16, N);
    int start = blockStart + wid * CHUNK;
    bool active = start < N;
    int pend = active ? min(start + CHUNK, N) : start;

    int sub = lane >> 4;
    int ch  = (lane & 15) << 2;

    int bblk = bidx[blockStart];
    bool blockUniform = (bidx[blockEnd - 1] == bblk);

    if (blockUniform) {
        float4 s0 = make_float4(0.f,0.f,0.f,0.f), s1 = s0, s2 = s0, s3 = s0;
        float4 m0 = make_float4(-INFINITY,-INFINITY,-INFINITY,-INFINITY);
        float4 m1 = m0, m2 = m0, m3 = m0;
        if (active) {
            const float* fb = F + (size_t)sub * INC + ch;
            int p = start;
            #pragma unroll 1
            for (; p + 16 <= pend; p += 16) {
                const float* fp = fb + (size_t)p * INC;
                float4 v0 = *reinterpret_cast<const float4*>(fp);
                float4 v1 = *reinterpret_cast<const float4*>(fp + 4 * INC);
                float4 v2 = *reinterpret_cast<const float4*>(fp + 8 * INC);
                float4 v3 = *reinterpret_cast<const float4*>(fp + 12 * INC);
                __builtin_amdgcn_sched_barrier(0);
                acc4(s0, m0, v0); acc4(s1, m1, v1);
                acc4(s2, m2, v2); acc4(s3, m3, v3);
            }
            #pragma unroll 1
            for (; p < pend; p += 4) {
                float4 v = *reinterpret_cast<const float4*>(fb + (size_t)p * INC);
                acc4(s0, m0, v);
            }
        }
        // merge 4 streams
        s0.x += s1.x + s2.x + s3.x; s0.y += s1.y + s2.y + s3.y;
        s0.z += s1.z + s2.z + s3.z; s0.w += s1.w + s2.w + s3.w;
        m0.x = fmaxf(fmaxf(m0.x, m1.x), fmaxf(m2.x, m3.x));
        m0.y = fmaxf(fmaxf(m0.y, m1.y), fmaxf(m2.y, m3.y));
        m0.z = fmaxf(fmaxf(m0.z, m1.z), fmaxf(m2.z, m3.z));
        m0.w = fmaxf(fmaxf(m0.w, m1.w), fmaxf(m2.w, m3.w));
        // combine the 4 sub-copies (lanes differing in bits 4,5)
        #pragma unroll
        for (int msk = 16; msk < 64; msk <<= 1) {
            s0.x += __shfl_xor(s0.x, msk); s0.y += __shfl_xor(s0.y, msk);
            s0.z += __shfl_xor(s0.z, msk); s0.w += __shfl_xor(s0.w, msk);
            m0.x = fmaxf(m0.x, __shfl_xor(m0.x, msk));
            m0.y = fmaxf(m0.y, __shfl_xor(m0.y, msk));
            m0.z = fmaxf(m0.z, __shfl_xor(m0.z, msk));
            m0.w = fmaxf(m0.w, __shfl_xor(m0.w, msk));
        }
        if (lane < 16) { lsum[wid][lane] = s0; lmax[wid][lane] = m0; }
        __syncthreads();
        if (wid == 0 && lane < 16) {
            float4 S = lsum[0][lane];
            float4 M = lmax[0][lane];
            #pragma unroll
            for (int w = 1; w < 16; ++w) {
                float4 a = lsum[w][lane], x = lmax[w][lane];
                S.x += a.x; S.y += a.y; S.z += a.z; S.w += a.w;
                M.x = fmaxf(M.x, x.x); M.y = fmaxf(M.y, x.y);
                M.z = fmaxf(M.z, x.z); M.w = fmaxf(M.w, x.w);
            }
            float* ss = seg_sum + bblk * INC + (lane << 2);
            atomicAdd(ss + 0, S.x); atomicAdd(ss + 1, S.y);
            atomicAdd(ss + 2, S.z); atomicAdd(ss + 3, S.w);
            float* sx = seg_max + bblk * INC + (lane << 2);
            atomicMaxF(sx + 0, M.x); atomicMaxF(sx + 1, M.y);
            atomicMaxF(sx + 2, M.z); atomicMaxF(sx + 3, M.w);
            if (lane == 0) atomicAdd(&counts[bblk], blockEnd - blockStart);
        }
        return;
    }

    // ---- non-uniform block (<=7 per launch): per-wave handling ----
    if (!active) return;
    int bfirst = bidx[start];
    int blast  = bidx[pend - 1];

    if (bfirst == blast) {
        float4 sum = make_float4(0.f,0.f,0.f,0.f);
        float4 mx  = make_float4(-INFINITY,-INFINITY,-INFINITY,-INFINITY);
        const float* fb = F + (size_t)sub * INC + ch;
        #pragma unroll 1
        for (int p = start; p < pend; p += 4) {
            float4 v = *reinterpret_cast<const float4*>(fb + (size_t)p * INC);
            acc4(sum, mx, v);
        }
        #pragma unroll
        for (int msk = 16; msk < 64; msk <<= 1) {
            sum.x += __shfl_xor(sum.x, msk); sum.y += __shfl_xor(sum.y, msk);
            sum.z += __shfl_xor(sum.z, msk); sum.w += __shfl_xor(sum.w, msk);
            mx.x = fmaxf(mx.x, __shfl_xor(mx.x, msk));
            mx.y = fmaxf(mx.y, __shfl_xor(mx.y, msk));
            mx.z = fmaxf(mx.z, __shfl_xor(mx.z, msk));
            mx.w = fmaxf(mx.w, __shfl_xor(mx.w, msk));
        }
        if (sub == 0) {
            float* ss = seg_sum + bfirst * INC + ch;
            atomicAdd(ss + 0, sum.x); atomicAdd(ss + 1, sum.y);
            atomicAdd(ss + 2, sum.z); atomicAdd(ss + 3, sum.w);
            float* sx = seg_max + bfirst * INC + ch;
            atomicMaxF(sx + 0, mx.x); atomicMaxF(sx + 1, mx.y);
            atomicMaxF(sx + 2, mx.z); atomicMaxF(sx + 3, mx.w);
            if (lane == 0) atomicAdd(&counts[bfirst], pend - start);
        }
        return;
    }

    bool isCnt = (lane & 15) == 0;
    float4 sum = make_float4(0.f,0.f,0.f,0.f);
    float4 mx  = make_float4(-INFINITY,-INFINITY,-INFINITY,-INFINITY);
    int cnt = 0, cur = -1;
    for (int p = start; p < pend; p += 4) {
        int pp = p + sub;
        int b = bidx[pp];
        if (b != cur) {
            if (cur >= 0) {
                float* ss = seg_sum + cur * INC + ch;
                atomicAdd(ss + 0, sum.x); atomicAdd(ss + 1, sum.y);
                atomicAdd(ss + 2, sum.z); atomicAdd(ss + 3, sum.w);
                float* sx = seg_max + cur * INC + ch;
                atomicMaxF(sx + 0, mx.x); atomicMaxF(sx + 1, mx.y);
                atomicMaxF(sx + 2, mx.z); atomicMaxF(sx + 3, mx.w);
                if (isCnt && cnt) atomicAdd(&counts[cur], cnt);
            }
            sum = make_float4(0.f,0.f,0.f,0.f);
            mx  = make_float4(-INFINITY,-INFINITY,-INFINITY,-INFINITY);
            cnt = 0; cur = b;
        }
        const float4 v = *reinterpret_cast<const float4*>(F + (size_t)pp * INC + ch);
        acc4(sum, mx, v);
        cnt += (int)isCnt;
    }
    if (cur >= 0) {
        float* ss = seg_sum + cur * INC + ch;
        atomicAdd(ss + 0, sum.x); atomicAdd(ss + 1, sum.y);
        atomicAdd(ss + 2, sum.z); atomicAdd(ss + 3, sum.w);
        float* sx = seg_max + cur * INC + ch;
        atomicMaxF(sx + 0, mx.x); atomicMaxF(sx + 1, mx.y);
        atomicMaxF(sx + 2, mx.z); atomicMaxF(sx + 3, mx.w);
        if (isCnt && cnt) atomicAdd(&counts[cur], cnt);
    }
}

// -------- tiny per-batch MLP: gate[b][c] = sigmoid(mlp(avg)+mlp(mx)) ---------
__global__ void k_gate(const float* __restrict__ seg_sum, const float* __restrict__ seg_max,
                       const int* __restrict__ counts,
                       const float* __restrict__ W1, const float* __restrict__ b1,
                       const float* __restrict__ W2, const float* __restrict__ b2,
                       float* __restrict__ gate) {
    __shared__ float s_avg[NB * INC], s_mx[NB * INC];
    __shared__ float s_W1[INC * HID], s_W2[HID * INC];
    __shared__ float s_ha[NB * HID], s_hm[NB * HID];
    int t = threadIdx.x; // 512 threads
    s_W1[t] = W1[t]; s_W1[t + 512] = W1[t + 512];
    s_W2[t] = W2[t]; s_W2[t + 512] = W2[t + 512];
    {
        int b = t >> 6;
        float c = (float)counts[b];
        s_avg[t] = seg_sum[t] / c;
        s_mx[t]  = seg_max[t];
    }
    __syncthreads();
    if (t < NB * HID) {
        int b = t >> 4, j = t & (HID - 1);
        float ha = b1[j], hm = b1[j];
        #pragma unroll
        for (int c = 0; c < INC; ++c) {
            float w = s_W1[c * HID + j];
            ha += s_avg[b * INC + c] * w;
            hm += s_mx[b * INC + c] * w;
        }
        s_ha[t] = fmaxf(ha, 0.f);
        s_hm[t] = fmaxf(hm, 0.f);
    }
    __syncthreads();
    {
        int b = t >> 6, c = t & 63;
        float o = 2.f * b2[c];
        #pragma unroll
        for (int j = 0; j < HID; ++j)
            o += (s_ha[b * HID + j] + s_hm[b * HID + j]) * s_W2[j * INC + c];
        gate[t] = 1.f / (1.f + expf(-o));
    }
}

// ------- per-point channel mean/max of z = F*gate -> sm[N][2] ---------------
__global__ void k_sm(const float* __restrict__ F, const int* __restrict__ bidx,
                     const float* __restrict__ gate, float* __restrict__ sm,
                     int N, int CHUNK) {
    int lane = threadIdx.x & 63;
    int wave = (blockIdx.x * blockDim.x + threadIdx.x) >> 6;
    int start = wave * CHUNK;
    if (start >= N) return;
    int pend = min(start + CHUNK, N);
    int sub = lane >> 4, ch = (lane & 15) << 2;
    bool wr = (lane & 15) == 0;

    int bfirst = bidx[start];
    int blast  = bidx[pend - 1];

    if (bfirst == blast) {
        const float4 g = *reinterpret_cast<const float4*>(gate + bfirst * INC + ch);
        const float* fb = F + (size_t)sub * INC + ch;
        int p = start;
        #pragma unroll 1
        for (; p + 16 <= pend; p += 16) {
            const float* fp = fb + (size_t)p * INC;
            float4 v0 = *reinterpret_cast<const float4*>(fp);
            float4 v1 = *reinterpret_cast<const float4*>(fp + 4 * INC);
            float4 v2 = *reinterpret_cast<const float4*>(fp + 8 * INC);
            float4 v3 = *reinterpret_cast<const float4*>(fp + 12 * INC);
            __builtin_amdgcn_sched_barrier(0);
            float s0, s1, s2, s3, m0, m1, m2, m3;
            {
                float4 z = make_float4(v0.x*g.x, v0.y*g.y, v0.z*g.z, v0.w*g.w);
                s0 = z.x + z.y + z.z + z.w; m0 = fmaxf(fmaxf(z.x, z.y), fmaxf(z.z, z.w));
            }
            {
                float4 z = make_float4(v1.x*g.x, v1.y*g.y, v1.z*g.z, v1.w*g.w);
                s1 = z.x + z.y + z.z + z.w; m1 = fmaxf(fmaxf(z.x, z.y), fmaxf(z.z, z.w));
            }
            {
                float4 z = make_float4(v2.x*g.x, v2.y*g.y, v2.z*g.z, v2.w*g.w);
                s2 = z.x + z.y + z.z + z.w; m2 = fmaxf(fmaxf(z.x, z.y), fmaxf(z.z, z.w));
            }
            {
                float4 z = make_float4(v3.x*g.x, v3.y*g.y, v3.z*g.z, v3.w*g.w);
                s3 = z.x + z.y + z.z + z.w; m3 = fmaxf(fmaxf(z.x, z.y), fmaxf(z.z, z.w));
            }
            #pragma unroll
            for (int msk = 1; msk < 16; msk <<= 1) {
                s0 += __shfl_xor(s0, msk); m0 = fmaxf(m0, __shfl_xor(m0, msk));
                s1 += __shfl_xor(s1, msk); m1 = fmaxf(m1, __shfl_xor(m1, msk));
                s2 += __shfl_xor(s2, msk); m2 = fmaxf(m2, __shfl_xor(m2, msk));
                s3 += __shfl_xor(s3, msk); m3 = fmaxf(m3, __shfl_xor(m3, msk));
            }
            if (wr) {
                *reinterpret_cast<float2*>(sm + (size_t)(p + sub) * 2)      = make_float2(s0 * (1.f/64.f), m0);
                *reinterpret_cast<float2*>(sm + (size_t)(p + 4 + sub) * 2)  = make_float2(s1 * (1.f/64.f), m1);
                *reinterpret_cast<float2*>(sm + (size_t)(p + 8 + sub) * 2)  = make_float2(s2 * (1.f/64.f), m2);
                *reinterpret_cast<float2*>(sm + (size_t)(p + 12 + sub) * 2) = make_float2(s3 * (1.f/64.f), m3);
            }
        }
        #pragma unroll 1
        for (; p < pend; p += 4) {
            float4 v = *reinterpret_cast<const float4*>(fb + (size_t)p * INC);
            float4 z = make_float4(v.x*g.x, v.y*g.y, v.z*g.z, v.w*g.w);
            float s = z.x + z.y + z.z + z.w;
            float m = fmaxf(fmaxf(z.x, z.y), fmaxf(z.z, z.w));
            #pragma unroll
            for (int msk = 1; msk < 16; msk <<= 1) {
                s += __shfl_xor(s, msk); m = fmaxf(m, __shfl_xor(m, msk));
            }
            if (wr) *reinterpret_cast<float2*>(sm + (size_t)(p + sub) * 2) = make_float2(s * (1.f/64.f), m);
        }
        return;
    }

    // slow path (<=7 waves): per-point gate gather
    for (int p = start; p < pend; p += 4) {
        int pp = p + sub;
        int b = bidx[pp];
        float4 v = *reinterpret_cast<const float4*>(F + (size_t)pp * INC + ch);
        float4 g = *reinterpret_cast<const float4*>(gate + b * INC + ch);
        float4 z = make_float4(v.x*g.x, v.y*g.y, v.z*g.z, v.w*g.w);
        float s = z.x + z.y + z.z + z.w;
        float m = fmaxf(fmaxf(z.x, z.y), fmaxf(z.z, z.w));
        #pragma unroll
        for (int msk = 1; msk < 16; msk <<= 1) {
            s += __shfl_xor(s, msk); m = fmaxf(m, __shfl_xor(m, msk));
        }
        if (wr) *reinterpret_cast<float2*>(sm + (size_t)pp * 2) = make_float2(s * (1.f/64.f), m);
    }
}

// ------- gather 27 neighbors' sm, 2ch conv, final out = z * sigmoid(c) ------
// Fast path: gathers double-buffered (issued one full iteration ahead),
// nbr indices two iterations ahead; all pinned by sched_barrier.
__global__ void k_out(const float* __restrict__ F, const int* __restrict__ bidx,
                      const int* __restrict__ nbr, const float* __restrict__ gate,
                      const float* __restrict__ sm, const float* __restrict__ cw,
                      float* __restrict__ out, int N, int CHUNK) {
    int lane = threadIdx.x & 63;
    int j = lane & 15;
    int sub = lane >> 4, ch = (lane & 15) << 2;
    float2 cwa = make_float2(cw[2 * j], cw[2 * j + 1]);
    float2 cwb = (j < 11) ? make_float2(cw[2 * (16 + j)], cw[2 * (16 + j) + 1])
                          : make_float2(0.f, 0.f);
    int wave = (blockIdx.x * blockDim.x + threadIdx.x) >> 6;
    int start = wave * CHUNK;
    if (start >= N) return;
    int pend = min(start + CHUNK, N);

    int bfirst = bidx[start];
    int blast  = bidx[pend - 1];

    if (bfirst == blast) {
        const float4 g = *reinterpret_cast<const float4*>(gate + bfirst * INC + ch);
        // prologue: gathers for iter 0 in flight, indices for iter 1 in flight
        int pp0 = start + sub;
        int i1 = nbr[pp0 * 27 + j];
        int i2 = (j < 11) ? nbr[pp0 * 27 + 16 + j] : N;
        float2 A  = *reinterpret_cast<const float2*>(sm + (size_t)i1 * 2);
        float2 Bv = *reinterpret_cast<const float2*>(sm + (size_t)i2 * 2);
        int np = pp0 + 4; if (np >= N) np = N - 1;
        int n1 = nbr[np * 27 + j];
        int n2 = (j < 11) ? nbr[np * 27 + 16 + j] : N;
        #pragma unroll 1
        for (int p = start; p < pend; p += 4) {
            // issue next iteration's gathers + F + next-next indices
            float2 A1 = *reinterpret_cast<const float2*>(sm + (size_t)n1 * 2);
            float2 B1 = *reinterpret_cast<const float2*>(sm + (size_t)n2 * 2);
            float4 v = *reinterpret_cast<const float4*>(F + (size_t)(p + sub) * INC + ch);
            int np2 = p + 8 + sub; if (np2 >= N) np2 = N - 1;
            int nn1 = nbr[np2 * 27 + j];
            int nn2 = (j < 11) ? nbr[np2 * 27 + 16 + j] : N;
            __builtin_amdgcn_sched_barrier(0);
            // consume gathers issued LAST iteration (already landed)
            float cpart = A.x * cwa.x + A.y * cwa.y + Bv.x * cwb.x + Bv.y * cwb.y;
            #pragma unroll
            for (int msk = 1; msk < 16; msk <<= 1) cpart += __shfl_xor(cpart, msk);
            float sig = 1.f / (1.f + expf(-cpart));
            float4 o = make_float4(v.x * g.x * sig, v.y * g.y * sig,
                                   v.z * g.z * sig, v.w * g.w * sig);
            *reinterpret_cast<float4*>(out + (size_t)(p + sub) * INC + ch) = o;
            A = A1; Bv = B1; n1 = nn1; n2 = nn2;
        }
        return;
    }

    // slow path (<=7 waves): per-point bidx + gate gather
    for (int p = start; p < pend; p += 4) {
        int pp = p + sub;
        int rb = pp * 27;
        int i1 = nbr[rb + j];
        int i2 = (j < 11) ? nbr[rb + 16 + j] : N;
        float2 a = *reinterpret_cast<const float2*>(sm + (size_t)i1 * 2);
        float2 b = *reinterpret_cast<const float2*>(sm + (size_t)i2 * 2);
        float cpart = a.x * cwa.x + a.y * cwa.y + b.x * cwb.x + b.y * cwb.y;
        #pragma unroll
        for (int msk = 1; msk < 16; msk <<= 1) cpart += __shfl_xor(cpart, msk);
        float sig = 1.f / (1.f + expf(-cpart));
        int bb = bidx[pp];
        float4 v = *reinterpret_cast<const float4*>(F + (size_t)pp * INC + ch);
        float4 g = *reinterpret_cast<const float4*>(gate + bb * INC + ch);
        float4 o = make_float4(v.x * g.x * sig, v.y * g.y * sig,
                               v.z * g.z * sig, v.w * g.w * sig);
        *reinterpret_cast<float4*>(out + (size_t)pp * INC + ch) = o;
    }
}

extern "C" void kernel_launch(void* const* d_in, const int* in_sizes, int n_in,
                              void* d_out, int out_size, void* d_ws, size_t ws_size,
                              hipStream_t stream) {
    const float* F    = (const float*)d_in[0];
    const int*   bidx = (const int*)d_in[1];
    const int*   nbr  = (const int*)d_in[2];
    const float* W1   = (const float*)d_in[3];
    const float* b1   = (const float*)d_in[4];
    const float* W2   = (const float*)d_in[5];
    const float* b2   = (const float*)d_in[6];
    const float* cw   = (const float*)d_in[7];
    float* out = (float*)d_out;
    int N = in_sizes[1];

    float* ws      = (float*)d_ws;
    float* seg_sum = ws;                 // 512
    float* seg_max = ws + NB * INC;      // 512
    int*   counts  = (int*)(ws + 2 * NB * INC); // 8
    float* gate    = ws + 2 * NB * INC + 16;    // 512
    float* sm      = ws + 3 * NB * INC + 32;    // (N+1)*2, 8B-aligned

    k_init<<<1, 1024, 0, stream>>>(seg_sum, seg_max, counts, sm + (size_t)N * 2);

    // k_reduce: 1024-thread blocks (16 waves), wave chunk 48 -> 391 blocks, 6256 waves
    {
        const int chunk = 48;
        int blocks = (N + chunk * 16 - 1) / (chunk * 16);
        k_reduce<<<blocks, 1024, 0, stream>>>(F, bidx, seg_sum, seg_max, counts, N, chunk);
    }

    k_gate<<<1, 512, 0, stream>>>(seg_sum, seg_max, counts, W1, b1, W2, b2, gate);

    // k_sm / k_out: chunk 32 -> 2344 blocks x 256 thr = 9376 waves (~37/CU requested)
    {
        const int chunk = 32;
        int blocks = (N + chunk * 4 - 1) / (chunk * 4);
        k_sm<<<blocks, 256, 0, stream>>>(F, bidx, gate, sm, N, chunk);
        k_out<<<blocks, 256, 0, stream>>>(F, bidx, nbr, gate, sm, cw, out, N, chunk);
    }
}